// Round 1
// 98.171 us; speedup vs baseline: 1.0038x; 1.0038x over previous
//
#include <hip/hip_runtime.h>

#define D_  128
#define B_  2
#define N1_ 500
#define N2_ 800

// ---------------------------------------------------------------------------
// Prologue: P1[b,n,f] = sum_k h1[b,n,k]*W1[k,f] + b1[f]
//           P2[b,m,f] = sum_k h2[b,m,k]*W1[D+k,f]
// v2: 4 rows/block (650 blocks -> 2.5 blocks/CU = 2.5 waves/SIMD) so the
// L2-hit W1 loads are latency-hidden by TLP, plus unroll 8 for ILP.
// c = tid&127 (output col, coalesced W1 column loads), rg = tid>>7 picks
// a 2-row group. 1000 and 1600 rows both divide by 4 -> no row guards.
// ---------------------------------------------------------------------------
__global__ __launch_bounds__(256) void proj_kernel(
    const float* __restrict__ h1, const float* __restrict__ h2,
    const float* __restrict__ W1, const float* __restrict__ b1,
    float* __restrict__ P1, float* __restrict__ P2)
{
    __shared__ float hs[4][128];
    const int NB1 = (B_ * N1_) / 4;   // 250 blocks for P1 (1000 rows)
    bool isP1 = (int)blockIdx.x < NB1;
    int r0 = (isP1 ? (int)blockIdx.x : (int)blockIdx.x - NB1) * 4;
    const float* __restrict__ src = isP1 ? h1 : h2;
    float* __restrict__ dst = isP1 ? P1 : P2;
    const int koff = isP1 ? 0 : D_;

    int tid = threadIdx.x;
    // stage 4 rows (128 float4, threads 0..127; wave-uniform branch)
    if (tid < 128) {
        int row = tid >> 5;
        int c4  = (tid & 31) * 4;
        *reinterpret_cast<float4*>(&hs[row][c4]) =
            *reinterpret_cast<const float4*>(&src[(size_t)(r0 + row) * D_ + c4]);
    }
    __syncthreads();

    int c  = tid & 127;
    int rg = tid >> 7;                 // 0/1 -> rows {0,1} / {2,3}
    const float* __restrict__ Wc = W1 + (size_t)koff * D_ + c;
    float binit = isP1 ? b1[c] : 0.f;
    float a0 = binit, a1 = binit;

    #pragma unroll 8
    for (int k4 = 0; k4 < D_; k4 += 4) {
        float w0 = Wc[(k4 + 0) * D_];
        float w1 = Wc[(k4 + 1) * D_];
        float w2 = Wc[(k4 + 2) * D_];
        float w3 = Wc[(k4 + 3) * D_];
        float4 ha = *reinterpret_cast<const float4*>(&hs[rg * 2 + 0][k4]);
        float4 hb = *reinterpret_cast<const float4*>(&hs[rg * 2 + 1][k4]);
        a0 = fmaf(ha.x, w0, a0);
        a0 = fmaf(ha.y, w1, a0);
        a0 = fmaf(ha.z, w2, a0);
        a0 = fmaf(ha.w, w3, a0);
        a1 = fmaf(hb.x, w0, a1);
        a1 = fmaf(hb.y, w1, a1);
        a1 = fmaf(hb.z, w2, a1);
        a1 = fmaf(hb.w, w3, a1);
    }
    dst[(size_t)(r0 + rg * 2 + 0) * D_ + c] = a0;
    dst[(size_t)(r0 + rg * 2 + 1) * D_ + c] = a1;
}

// ---------------------------------------------------------------------------
// Pair kernel: block tile = 16 n x 128 m. 4 waves; wave w owns n-rows
// [4w,4w+4); each lane owns TWO m columns (lane, lane+64). Tail m-tile
// (m0=768, only 32 real columns) takes a wave-uniform single-column path.
// p2 rows padded to stride 132: b128 reads -> 8 lanes cover all 32 banks
// per phase (structural 8-phase floor). LDS ~76KB -> 2 blocks/CU.
// v2: W2 + m1 read via wave-uniform global loads (s_load path, no LDS
// staging for them); contact prefetched into registers BEFORE the barrier
// so its latency overlaps staging instead of sitting exposed in the
// epilogue; full-tile staging drops the row guard.
// ---------------------------------------------------------------------------
__global__ __launch_bounds__(256) void pair_kernel(
    const int* __restrict__ S1, const int* __restrict__ S2,
    const float* __restrict__ contact,
    const float* __restrict__ P1, const float* __restrict__ P2,
    const float* __restrict__ W2, const float* __restrict__ b2,
    float* __restrict__ out)
{
    const int NT = 16, MT = 128;
    const int nTn = (N1_ + NT - 1) / NT;    // 32
    const int nTm = (N2_ + MT - 1) / MT;    // 7
    int bid = blockIdx.x;
    int tb  = bid / (nTn * nTm);
    int rem = bid % (nTn * nTm);
    int tn  = rem / nTm;
    int tm  = rem % nTm;
    int n0 = tn * NT, m0 = tm * MT;
    int tid = threadIdx.x, lane = tid & 63, wave = tid >> 6;
    bool fullTile = (m0 + MT <= N2_);       // block-uniform

    __shared__ float p2s[128 * 132];  // 67.6 KB, padded stride
    __shared__ float p1s[16 * 128];   // 8 KB

    // stage P2 tile (128 rows x 128 floats)
    const float* __restrict__ P2b = P2 + ((size_t)tb * N2_ + m0) * D_;
    if (fullTile) {
        #pragma unroll
        for (int j = 0; j < 16; ++j) {
            int fi  = tid + j * 256;      // 4096 float4s
            int row = fi >> 5;
            int c4  = (fi & 31) * 4;
            *reinterpret_cast<float4*>(&p2s[row * 132 + c4]) =
                *reinterpret_cast<const float4*>(&P2b[row * D_ + c4]);
        }
    } else {
        #pragma unroll
        for (int j = 0; j < 16; ++j) {
            int fi  = tid + j * 256;
            int row = fi >> 5;
            int c4  = (fi & 31) * 4;
            float4 v = make_float4(0.f, 0.f, 0.f, 0.f);
            if (m0 + row < N2_) v = *reinterpret_cast<const float4*>(&P2b[row * D_ + c4]);
            *reinterpret_cast<float4*>(&p2s[row * 132 + c4]) = v;
        }
    }
    // stage P1 tile (guarded: tn=31 has rows 496..511, only 500 valid)
    const float* __restrict__ P1b = P1 + ((size_t)tb * N1_ + n0) * D_;
    #pragma unroll
    for (int j = 0; j < 2; ++j) {
        int fi  = tid + j * 256;
        int row = fi >> 5;
        int c4  = (fi & 31) * 4;
        float4 v = make_float4(0.f, 0.f, 0.f, 0.f);
        if (n0 + row < N1_) v = *reinterpret_cast<const float4*>(&P1b[row * D_ + c4]);
        *reinterpret_cast<float4*>(&p1s[row * 128 + c4]) = v;
    }

    // hoist ALL epilogue globals before the barrier: the barrier's
    // vmcnt(0) drain makes their latency free (overlaps staging loads).
    int nw = wave * 4;
    int mA = m0 + lane;
    int mB = m0 + 64 + lane;
    float m2A = (mA < N2_ && S2[tb * N2_ + mA] != 0) ? 1.f : 0.f;
    float m2B = (fullTile && S2[tb * N2_ + mB] != 0) ? 1.f : 0.f;
    float bias2 = b2[0];

    const size_t NN  = (size_t)N1_ * N2_;   // 400000
    const size_t TOT = (size_t)B_ * NN;     // 800000
    float m1v[4], cvA[4], cvB[4];
    #pragma unroll
    for (int i = 0; i < 4; ++i) {
        int n = n0 + nw + i;
        bool nok = (n < N1_);
        // wave-uniform address -> scalar load
        m1v[i] = (nok && S1[tb * N1_ + n] != 0) ? 1.f : 0.f;
        size_t rowoff = (size_t)tb * NN + (size_t)n * N2_;
        cvA[i] = (nok && mA < N2_) ? contact[rowoff + mA] : 1.f;
        cvB[i] = (nok && fullTile) ? contact[rowoff + mB] : 1.f;
    }
    __syncthreads();

    float acc0[4] = {0.f, 0.f, 0.f, 0.f};
    float acc1[4] = {0.f, 0.f, 0.f, 0.f};
    const float* p2a = &p2s[lane * 132];
    const float* p2b = &p2s[(lane + 64) * 132];
    const float* p1p = &p1s[nw * 128];

    if (fullTile) {
        #pragma unroll 4
        for (int d = 0; d < D_; d += 4) {
            float4 qa = *reinterpret_cast<const float4*>(&p2a[d]);
            float4 qb = *reinterpret_cast<const float4*>(&p2b[d]);
            // wave-uniform address -> s_load, no LDS traffic
            float4 w  = *reinterpret_cast<const float4*>(&W2[d]);
            #pragma unroll
            for (int i = 0; i < 4; ++i) {
                float4 q1 = *reinterpret_cast<const float4*>(&p1p[i * 128 + d]);
                acc0[i] = fmaf(fmaxf(q1.x + qa.x, 0.f), w.x, acc0[i]);
                acc0[i] = fmaf(fmaxf(q1.y + qa.y, 0.f), w.y, acc0[i]);
                acc0[i] = fmaf(fmaxf(q1.z + qa.z, 0.f), w.z, acc0[i]);
                acc0[i] = fmaf(fmaxf(q1.w + qa.w, 0.f), w.w, acc0[i]);
                acc1[i] = fmaf(fmaxf(q1.x + qb.x, 0.f), w.x, acc1[i]);
                acc1[i] = fmaf(fmaxf(q1.y + qb.y, 0.f), w.y, acc1[i]);
                acc1[i] = fmaf(fmaxf(q1.z + qb.z, 0.f), w.z, acc1[i]);
                acc1[i] = fmaf(fmaxf(q1.w + qb.w, 0.f), w.w, acc1[i]);
            }
        }
    } else {
        // tail tile: only columns [m0, N2) exist; single-column path
        #pragma unroll 4
        for (int d = 0; d < D_; d += 4) {
            float4 qa = *reinterpret_cast<const float4*>(&p2a[d]);
            float4 w  = *reinterpret_cast<const float4*>(&W2[d]);
            #pragma unroll
            for (int i = 0; i < 4; ++i) {
                float4 q1 = *reinterpret_cast<const float4*>(&p1p[i * 128 + d]);
                acc0[i] = fmaf(fmaxf(q1.x + qa.x, 0.f), w.x, acc0[i]);
                acc0[i] = fmaf(fmaxf(q1.y + qa.y, 0.f), w.y, acc0[i]);
                acc0[i] = fmaf(fmaxf(q1.z + qa.z, 0.f), w.z, acc0[i]);
                acc0[i] = fmaf(fmaxf(q1.w + qa.w, 0.f), w.w, acc0[i]);
            }
        }
    }

    // fused epilogue: pred (unmasked), y_contact, mask — coalesced along m
    #pragma unroll
    for (int i = 0; i < 4; ++i) {
        int n = n0 + nw + i;
        if (n >= N1_) break;
        float m1 = m1v[i];
        size_t rowoff = (size_t)tb * NN + (size_t)n * N2_;
        if (mA < N2_) {
            float mk = m1 * m2A;
            size_t off = rowoff + mA;
            out[off]           = acc0[i] + bias2;
            out[TOT + off]     = (cvA[i] < 0.5f) ? mk : 0.f;
            out[2 * TOT + off] = mk;
        }
        if (fullTile) {
            float mk = m1 * m2B;
            size_t off = rowoff + mB;
            out[off]           = acc1[i] + bias2;
            out[TOT + off]     = (cvB[i] < 0.5f) ? mk : 0.f;
            out[2 * TOT + off] = mk;
        }
    }
}

extern "C" void kernel_launch(void* const* d_in, const int* in_sizes, int n_in,
                              void* d_out, int out_size, void* d_ws, size_t ws_size,
                              hipStream_t stream) {
    const int*   S1      = (const int*)d_in[0];
    const int*   S2      = (const int*)d_in[1];
    const float* h1      = (const float*)d_in[2];
    const float* h2      = (const float*)d_in[3];
    const float* contact = (const float*)d_in[4];
    const float* W1      = (const float*)d_in[5];
    const float* b1      = (const float*)d_in[6];
    const float* W2      = (const float*)d_in[7];
    const float* b2      = (const float*)d_in[8];
    float* out = (float*)d_out;

    float* P1 = (float*)d_ws;                         // B*N1*D floats
    float* P2 = P1 + (size_t)B_ * N1_ * D_;           // B*N2*D floats

    const int projBlocks = (B_ * N1_) / 4 + (B_ * N2_) / 4;  // 250 + 400 = 650
    proj_kernel<<<projBlocks, 256, 0, stream>>>(h1, h2, W1, b1, P1, P2);

    const int pairBlocks = B_ * ((N1_ + 15) / 16) * ((N2_ + 127) / 128); // 448
    pair_kernel<<<pairBlocks, 256, 0, stream>>>(S1, S2, contact, P1, P2, W2, b2, out);
}